// Round 9
// baseline (542.757 us; speedup 1.0000x reference)
//
#include <hip/hip_runtime.h>
#include <stdint.h>

typedef __attribute__((ext_vector_type(8))) short short8;
typedef __attribute__((ext_vector_type(4))) float f32x4;
typedef __attribute__((ext_vector_type(4))) int i32x4;
typedef __attribute__((ext_vector_type(8))) unsigned short ushort8v;

#define NEGINF_F (-1000000.0f)
#define MFMA16 __builtin_amdgcn_mfma_f32_16x16x32_bf16

__device__ __forceinline__ unsigned short f2bf(float f) {
  union { float f; uint32_t u; } v; v.f = f;
  uint32_t r = (v.u + 0x7FFFu + ((v.u >> 16) & 1u)) >> 16;
  return (unsigned short)r;
}
__device__ __forceinline__ void gl_lds16(const void* g, void* l) {
  __builtin_amdgcn_global_load_lds(
      (const __attribute__((address_space(1))) void*)g,
      (__attribute__((address_space(3))) void*)l, 16, 0, 0);
}

// ---------------------------------------------------------------------------
// 128x128 GEMM body: C = A @ B^T, bf16 in, mfma 16x16x32 fp32 accum. BK=32,
// 256 thr = 4 waves (2x2), 4x4 frags/wave.
// K-loop: r3/r8-VERIFIED 2-buffer __syncthreads pipeline.
// OUT32: fp32 C via LDS-staged vectorized epilogue.
// MASKED: 1-bit-per-element bitmask (packed in prep) -> NEGINF. Replaces the
// 134 MB int32 mask read (which capped gemm_sc at 3 TB/s, r8 counters) with
// a 4.2 MB L2/L3-resident bit table: one u32 per thread per row-group.
// ---------------------------------------------------------------------------
template<bool OUT32, bool MASKED>
__device__ __forceinline__ void gemm_body(
    const unsigned short* __restrict__ Ap, const unsigned short* __restrict__ Bp,
    void* __restrict__ Cp, const unsigned int* __restrict__ bmp,
    int K, int lda, int ldb, int ldc, int tm, int tn, float scale,
    unsigned short* lds)
{
  const int t = threadIdx.x;
  const int lane = t & 63, wave = t >> 6;
  const int wm = (wave & 1) * 64, wn = (wave >> 1) * 64;
  const int q = lane >> 4, mr = lane & 15;

  f32x4 acc[4][4];
#pragma unroll
  for (int i = 0; i < 4; i++)
#pragma unroll
    for (int j = 0; j < 4; j++) acc[i][j] = (f32x4){0.f, 0.f, 0.f, 0.f};

  const int r0a = t >> 2;                              // staging row
  const int cswz = ((t & 3) ^ ((t >> 2) & 3)) * 8;     // source pre-swizzle
  const int sw8 = (q ^ (mr & 3)) * 8;                  // frag-read swizzle

  auto stage = [&](int bi, int kt) {
    unsigned short* L = lds + bi * 8192;               // A [0,4096) B [4096,8192)
    const int k0 = kt << 5;
    const unsigned short* ga = Ap + (long)(tm + r0a) * lda + k0 + cswz;
    gl_lds16(ga, L + (size_t)t * 8);
    gl_lds16(ga + (long)64 * lda, L + (size_t)(t + 256) * 8);
    unsigned short* Lb = L + 4096;
    const unsigned short* gb = Bp + (long)(tn + r0a) * ldb + k0 + cswz;
    gl_lds16(gb, Lb + (size_t)t * 8);
    gl_lds16(gb + (long)64 * ldb, Lb + (size_t)(t + 256) * 8);
  };

  const int nt = K >> 5;
  stage(0, 0);
  __syncthreads();

  for (int ti = 0; ti < nt; ++ti) {
    if (ti + 1 < nt) stage((ti + 1) & 1, ti + 1);      // prefetch next

    const unsigned short* LA = lds + (ti & 1) * 8192;
    const unsigned short* LB = LA + 4096;
    short8 af[4], bfr[4];
#pragma unroll
    for (int i = 0; i < 4; i++) {
      af[i]  = *(const short8*)&LA[(size_t)(wm + i * 16 + mr) * 32 + sw8];
      bfr[i] = *(const short8*)&LB[(size_t)(wn + i * 16 + mr) * 32 + sw8];
    }
#pragma unroll
    for (int i = 0; i < 4; i++)
#pragma unroll
      for (int j = 0; j < 4; j++)
        acc[i][j] = MFMA16(af[i], bfr[j], acc[i][j], 0, 0, 0);

    if (ti + 1 < nt) __syncthreads();
  }

  // C/D layout (m89-verified): col = lane&15, row = (lane>>4)*4 + reg
  if (OUT32) {
    float* ep = (float*)lds;
    float* co = (float*)Cp;
    const int band = wm >> 2;                 // 0 or 16
    const int tr = t >> 3;                    // 0..31 read row
    const int tcb = (t & 7) * 16;             // read col base (mult of 16)
    const int growb = tm + (tr >> 4) * 64 + (tr & 15);
    const int ldw = ldc >> 5;                 // bitmask words per row
#pragma unroll
    for (int i = 0; i < 4; i++) {
      __syncthreads();
#pragma unroll
      for (int j = 0; j < 4; j++) {
        const int colb = wn + j * 16 + mr;
#pragma unroll
        for (int r = 0; r < 4; r++) {
          const int lr = band + q * 4 + r;
          ep[lr * 128 + ((colb + lr * 4) & 127)] = acc[i][j][r];
        }
      }
      __syncthreads();
      const int gr = growb + i * 16;
      const long rbase = (long)gr * ldc;
      const float* eprow = ep + tr * 128;
      const int rot = tr * 4;
      // one bit-word covers this thread's 16 cols (tn%128==0, tcb%16==0)
      unsigned int mw = 0;
      if (MASKED) mw = bmp[(size_t)gr * ldw + ((tn + tcb) >> 5)];
      const int bb = tcb & 16;                // bit base within the word
#pragma unroll
      for (int k = 0; k < 4; k++) {
        const int lc = tcb + k * 4;
        f32x4 x = *(const f32x4*)&eprow[(lc + rot) & 127];
        x *= scale;
        if (MASKED) {
#pragma unroll
          for (int e = 0; e < 4; e++)
            if (!((mw >> (bb + k * 4 + e)) & 1u)) x[e] = NEGINF_F;
        }
        *(f32x4*)&co[rbase + tn + lc] = x;
      }
    }
  } else {
    unsigned short* co = (unsigned short*)Cp;
#pragma unroll
    for (int i = 0; i < 4; i++)
#pragma unroll
      for (int j = 0; j < 4; j++) {
        const int row0 = tm + wm + i * 16 + q * 4;
        const int col  = tn + wn + j * 16 + mr;
#pragma unroll
        for (int r = 0; r < 4; r++)
          co[(long)(row0 + r) * ldc + col] = f2bf(acc[i][j][r] * scale);
      }
  }
}

// proj3: roles by (blockIdx.z + zoff):
//  z=0/1: Q/K projection  A=Xqkb[z] [16384x512], B=Wt[z], C=QK[z] (bf16, scaled)
//  z=2:   Vw^T per batch  A=Wtv [512x512], B=Xvb_b [2048x512], C=Vwt_b [512x2048]
__global__ __launch_bounds__(256, 4) void proj3(
    const unsigned short* __restrict__ Xqkb, const unsigned short* __restrict__ Wtqk,
    unsigned short* __restrict__ QK,
    const unsigned short* __restrict__ Wtv, const unsigned short* __restrict__ Xvb,
    unsigned short* __restrict__ Vwt, float sc, int zoff)
{
  __shared__ __align__(16) unsigned short lds[16384];
  const int zz = blockIdx.z + zoff;
  if (zz < 2) {
    gemm_body<false, false>(Xqkb + (size_t)zz * 8388608, Wtqk + zz * 262144,
        QK + (size_t)zz * 8388608, nullptr, 512, 512, 512, 512,
        blockIdx.x * 128, blockIdx.y * 128, sc, lds);
  } else {
    const int bb = blockIdx.x >> 2;
    gemm_body<false, false>(Wtv, Xvb + (size_t)bb * 1048576,
        Vwt + (size_t)bb * 1048576, nullptr, 512, 512, 512, 2048,
        (blockIdx.x & 3) * 128, blockIdx.y * 128, 1.0f, lds);
  }
}

// scores: per batch Qs_b @ Ks_b^T, bitmask epilogue -> P fp32
__global__ __launch_bounds__(256, 4) void gemm_sc(
    const unsigned short* __restrict__ Qs, const unsigned short* __restrict__ Ks,
    float* __restrict__ P, const unsigned int* __restrict__ BM)
{
  __shared__ __align__(16) unsigned short lds[16384];
  const int b = blockIdx.z;
  gemm_body<true, true>(Qs + (size_t)b * 1048576, Ks + (size_t)b * 1048576,
      P + (size_t)b * 4194304, BM + (size_t)b * 131072,
      512, 512, 512, 2048, blockIdx.x * 128, blockIdx.y * 128, 1.0f, lds);
}

// z: per batch Pb_b [2048x2048] @ Vwt_b^T [512x2048] -> z fp32 [2048x512]
__global__ __launch_bounds__(256, 4) void gemm_z(
    const unsigned short* __restrict__ Pb, const unsigned short* __restrict__ Vwt,
    float* __restrict__ z)
{
  __shared__ __align__(16) unsigned short lds[16384];
  const int b = blockIdx.z;
  gemm_body<true, false>(Pb + (size_t)b * 4194304, Vwt + (size_t)b * 1048576,
      z + (size_t)b * 1048576, nullptr,
      2048, 2048, 2048, 512, blockIdx.x * 128, blockIdx.y * 128, 1.0f, lds);
}

// ---------------------------------------------------------------------------
// 128x128 gemm_nt (r5-verified): fallback path only (A32 PV + z GEMM).
// ---------------------------------------------------------------------------
template<bool A32, bool OUT32>
__global__ __launch_bounds__(256, A32 ? 2 : 4)
void gemm_nt(const void* __restrict__ Av, const unsigned short* __restrict__ B,
             void* __restrict__ Cv,
             int K, int lda, int ldb, int ldc,
             long sA, long sB, long sC, float scale)
{
  constexpr int ABYTES = A32 ? 128 * 32 * 4 : 128 * 32 * 2;
  constexpr int BBYTES = 128 * 32 * 2;
  constexpr int BUFB = ABYTES + BBYTES;
  __shared__ __align__(16) unsigned char smem[2 * BUFB];

  const int t = threadIdx.x;
  const int b = blockIdx.z;
  const float* Af = (const float*)Av + (long)b * sA;
  const unsigned short* Ah = (const unsigned short*)Av + (long)b * sA;
  const unsigned short* Bp = B + (long)b * sB;
  const int tm = blockIdx.x * 128;
  const int tn = blockIdx.y * 128;

  const int lane = t & 63, wave = t >> 6;
  const int wm = (wave & 1) * 64, wn = (wave >> 1) * 64;
  const int q = lane >> 4, mr = lane & 15;

  f32x4 acc[4][4];
#pragma unroll
  for (int i = 0; i < 4; i++)
#pragma unroll
    for (int j = 0; j < 4; j++) acc[i][j] = (f32x4){0.f, 0.f, 0.f, 0.f};

  const int r0a = t >> 2;
  const int cswz = ((t & 3) ^ ((t >> 2) & 3)) * 8;
  const int sw8 = (q ^ (mr & 3)) * 8;

  auto stage = [&](int buf, int k0) {
    unsigned char* base = smem + buf * BUFB;
    if (A32) {
      float* Asf = (float*)base;
#pragma unroll
      for (int rd = 0; rd < 4; rd++) {
        const int f = rd * 1024 + t * 4;
        const int row = f >> 5, col = f & 31;
        gl_lds16(Af + (long)(tm + row) * lda + k0 + col, Asf + f);
      }
    } else {
      unsigned short* Ash = (unsigned short*)base;
      const unsigned short* ga = Ah + (long)(tm + r0a) * lda + k0 + cswz;
      gl_lds16(ga, &Ash[(size_t)t * 8]);
      gl_lds16(ga + (long)64 * lda, &Ash[(size_t)(t + 256) * 8]);
    }
    unsigned short* Bsb = (unsigned short*)(base + ABYTES);
    const unsigned short* gb = Bp + (long)(tn + r0a) * ldb + k0 + cswz;
    gl_lds16(gb, &Bsb[(size_t)t * 8]);
    gl_lds16(gb + (long)64 * ldb, &Bsb[(size_t)(t + 256) * 8]);
  };

  const int nt = K >> 5;
  stage(0, 0);
  __syncthreads();

  for (int ti = 0; ti < nt; ++ti) {
    if (ti + 1 < nt) stage((ti + 1) & 1, (ti + 1) << 5);

    const unsigned char* base = smem + (ti & 1) * BUFB;
    const unsigned short* Bs = (const unsigned short*)(base + ABYTES);
    short8 af[4], bfr[4];
#pragma unroll
    for (int i = 0; i < 4; i++) {
      if (A32) {
        const float* Asf = (const float*)base;
        const int fb = (wm + i * 16 + mr) * 32 + q * 8;
        const f32x4 x0 = *(const f32x4*)&Asf[fb];
        const f32x4 x1 = *(const f32x4*)&Asf[fb + 4];
        short8 v;
        v[0] = (short)f2bf(x0[0]); v[1] = (short)f2bf(x0[1]);
        v[2] = (short)f2bf(x0[2]); v[3] = (short)f2bf(x0[3]);
        v[4] = (short)f2bf(x1[0]); v[5] = (short)f2bf(x1[1]);
        v[6] = (short)f2bf(x1[2]); v[7] = (short)f2bf(x1[3]);
        af[i] = v;
      } else {
        const unsigned short* Ash = (const unsigned short*)base;
        af[i] = *(const short8*)&Ash[(size_t)(wm + i * 16 + mr) * 32 + sw8];
      }
      bfr[i] = *(const short8*)&Bs[(size_t)(wn + i * 16 + mr) * 32 + sw8];
    }
#pragma unroll
    for (int i = 0; i < 4; i++)
#pragma unroll
      for (int j = 0; j < 4; j++)
        acc[i][j] = MFMA16(af[i], bfr[j], acc[i][j], 0, 0, 0);

    if (ti + 1 < nt) __syncthreads();
  }

  if (OUT32) {
    float* ep = (float*)smem;
    float* co = (float*)Cv + (long)b * sC;
    const int band = wm >> 2;
    const int tr = t >> 3;
    const int tcb = (t & 7) * 16;
    const int growb = tm + (tr >> 4) * 64 + (tr & 15);
#pragma unroll
    for (int i = 0; i < 4; i++) {
      __syncthreads();
#pragma unroll
      for (int j = 0; j < 4; j++) {
        const int colb = wn + j * 16 + mr;
#pragma unroll
        for (int r = 0; r < 4; r++) {
          const int lr = band + q * 4 + r;
          ep[lr * 128 + ((colb + lr * 4) & 127)] = acc[i][j][r];
        }
      }
      __syncthreads();
      const int gr = growb + i * 16;
      const long rbase = (long)gr * ldc;
      const float* eprow = ep + tr * 128;
      const int rot = tr * 4;
#pragma unroll
      for (int k = 0; k < 4; k++) {
        const int lc = tcb + k * 4;
        f32x4 x = *(const f32x4*)&eprow[(lc + rot) & 127];
        x *= scale;
        *(f32x4*)&co[rbase + tn + lc] = x;
      }
    }
  } else {
#pragma unroll
    for (int i = 0; i < 4; i++) {
#pragma unroll
      for (int j = 0; j < 4; j++) {
        const int row0 = tm + wm + i * 16 + q * 4;
        const int col  = tn + wn + j * 16 + mr;
        const f32x4 v = acc[i][j];
#pragma unroll
        for (int r = 0; r < 4; r++) {
          float x = v[r] * scale;
          ((unsigned short*)Cv + (long)b * sC)[(long)(row0 + r) * ldc + col] = f2bf(x);
        }
      }
    }
  }
}

// one block per row of 2048 fp32 logits (mask pre-applied as NEGINF upstream):
// max -> sumexp -> normalize in place; optional bf16 copy to Pb.
__global__ __launch_bounds__(256) void softmax_rows_f32(
    float* __restrict__ P, unsigned short* __restrict__ Pb)
{
  const size_t row = blockIdx.x;
  float* p = P + row * 2048;
  const int t = threadIdx.x, lane = t & 63, wv = t >> 6;
  f32x4 a = *(const f32x4*)(p + t * 8);
  f32x4 c = *(const f32x4*)(p + t * 8 + 4);
  float x[8] = {a[0], a[1], a[2], a[3], c[0], c[1], c[2], c[3]};
  float mx = x[0];
#pragma unroll
  for (int j = 1; j < 8; j++) mx = fmaxf(mx, x[j]);
#pragma unroll
  for (int o = 32; o > 0; o >>= 1) mx = fmaxf(mx, __shfl_xor(mx, o));
  __shared__ float rm[4], rs[4];
  if (lane == 0) rm[wv] = mx;
  __syncthreads();
  mx = fmaxf(fmaxf(rm[0], rm[1]), fmaxf(rm[2], rm[3]));
  float e[8], s = 0.f;
#pragma unroll
  for (int j = 0; j < 8; j++) { e[j] = __expf(x[j] - mx); s += e[j]; }
#pragma unroll
  for (int o = 32; o > 0; o >>= 1) s += __shfl_xor(s, o);
  if (lane == 0) rs[wv] = s;
  __syncthreads();
  s = rs[0] + rs[1] + rs[2] + rs[3];
  // fully-masked row: mx stays NEGINF -> reference (softmax * mask) = 0
  const float linv = (mx < -1.0e5f) ? 0.f : 1.f / s;
  f32x4 o0 = {e[0] * linv, e[1] * linv, e[2] * linv, e[3] * linv};
  f32x4 o1 = {e[4] * linv, e[5] * linv, e[6] * linv, e[7] * linv};
  *(f32x4*)(p + t * 8) = o0;
  *(f32x4*)(p + t * 8 + 4) = o1;
  if (Pb) {
    ushort8v ob;
    ob[0] = f2bf(o0[0]); ob[1] = f2bf(o0[1]); ob[2] = f2bf(o0[2]); ob[3] = f2bf(o0[3]);
    ob[4] = f2bf(o1[0]); ob[5] = f2bf(o1[1]); ob[6] = f2bf(o1[2]); ob[7] = f2bf(o1[3]);
    *(ushort8v*)(Pb + row * 2048 + t * 8) = ob;
  }
}

// per-batch transpose+convert (fallback path only)
__global__ __launch_bounds__(256) void cvt_t_v(
    const float* __restrict__ src, unsigned short* __restrict__ dst)
{
  const int b = blockIdx.z;
  __shared__ float tile[32][33];
  const int s0 = blockIdx.x * 32, i0 = blockIdx.y * 32;
  const int tx = threadIdx.x & 31, ty = threadIdx.x >> 5;
#pragma unroll
  for (int r = 0; r < 4; r++) {
    const int srow = ty + r * 8;
    tile[srow][tx] = src[((size_t)b * 2048 + s0 + srow) * 512 + i0 + tx];
  }
  __syncthreads();
#pragma unroll
  for (int r = 0; r < 4; r++) {
    const int irow = ty + r * 8;
    dst[((size_t)b * 512 + i0 + irow) * 2048 + s0 + tx] = f2bf(tile[tx][irow]);
  }
}

// prep: fused cvt3 (x<4096) + transpose_w (4096<=x<4352) + mask bitpack
// (y==0, 4352<=x<8448: 32 int32 -> 1 u32 bit-word per thread).
__global__ __launch_bounds__(256) void prep(
    const float* __restrict__ Xq, const float* __restrict__ Xk,
    const float* __restrict__ Xv,
    unsigned short* __restrict__ dq, unsigned short* __restrict__ dk,
    unsigned short* __restrict__ dv,
    const float* __restrict__ W0, const float* __restrict__ W1,
    const float* __restrict__ W2,
    unsigned short* __restrict__ T0, unsigned short* __restrict__ T1,
    unsigned short* __restrict__ T2,
    const int* __restrict__ mk, unsigned int* __restrict__ BM)
{
  const int y = blockIdx.y;
  if (blockIdx.x < 4096) {
    const float* s = y == 0 ? Xq : (y == 1 ? Xk : Xv);
    unsigned short* d = y == 0 ? dq : (y == 1 ? dk : dv);
    const size_t i = ((size_t)blockIdx.x * 256 + threadIdx.x) * 8;
    const float4 a = *(const float4*)(s + i);
    const float4 b = *(const float4*)(s + i + 4);
    ushort8v o;
    o[0] = f2bf(a.x); o[1] = f2bf(a.y); o[2] = f2bf(a.z); o[3] = f2bf(a.w);
    o[4] = f2bf(b.x); o[5] = f2bf(b.y); o[6] = f2bf(b.z); o[7] = f2bf(b.w);
    *(ushort8v*)(d + i) = o;
  } else if (blockIdx.x < 4352) {
    const float* W = y == 0 ? W0 : (y == 1 ? W1 : W2);
    unsigned short* T = y == 0 ? T0 : (y == 1 ? T1 : T2);
    __shared__ float tile[32][33];
    const int id = blockIdx.x - 4096;            // 0..255 -> 16x16 tiles
    const int bx = (id & 15) * 32, by = (id >> 4) * 32;
    const int tx = threadIdx.x & 31, ty = threadIdx.x >> 5;
#pragma unroll
    for (int i = 0; i < 4; i++) {
      const int r = ty + i * 8;
      tile[r][tx] = W[(size_t)(by + r) * 512 + bx + tx];
    }
    __syncthreads();
#pragma unroll
    for (int i = 0; i < 4; i++) {
      const int r = ty + i * 8;
      T[(size_t)(bx + r) * 512 + by + tx] = f2bf(tile[tx][r]);
    }
  } else if (y == 0) {
    // bitpack: word gid covers mask ints [gid*32, gid*32+32)
    const size_t gid = (size_t)(blockIdx.x - 4352) * 256 + threadIdx.x;
    const int* mp = mk + gid * 32;
    unsigned int bits = 0;
#pragma unroll
    for (int p = 0; p < 8; p++) {
      const i32x4 v = *(const i32x4*)(mp + p * 4);
      bits |= (v[0] != 0 ? 1u : 0u) << (p * 4)
           |  (v[1] != 0 ? 1u : 0u) << (p * 4 + 1)
           |  (v[2] != 0 ? 1u : 0u) << (p * 4 + 2)
           |  (v[3] != 0 ? 1u : 0u) << (p * 4 + 3);
    }
    BM[gid] = bits;
  }
}

extern "C" void kernel_launch(void* const* d_in, const int* in_sizes, int n_in,
                              void* d_out, int out_size, void* d_ws, size_t ws_size,
                              hipStream_t stream) {
  const float* Xq = (const float*)d_in[0];
  const float* Xk = (const float*)d_in[1];
  const float* Xv = (const float*)d_in[2];
  const int*   mk = (const int*)d_in[3];
  const float* Wq = (const float*)d_in[4];
  const float* Wk = (const float*)d_in[5];
  const float* Wv = (const float*)d_in[6];

  float* z = (float*)d_out;                          // [8,2048,512] fp32
  float* P = z + (size_t)8 * 2048 * 512;             // [8,2048,2048] fp32

  // ws layout (bf16 shorts): Wtq|Wtk|Wtv (3x262144), buf1 (8388608),
  // buf2 (8388608), Pb (33554432) -> 102236160 bytes total.
  unsigned short* w    = (unsigned short*)d_ws;
  unsigned short* Wtq  = w;
  unsigned short* Wtv  = w + 524288;
  unsigned short* buf1 = w + 786432;                 // Qs; later Vwt
  unsigned short* buf2 = buf1 + 8388608;             // Ks
  unsigned short* Pb   = buf2 + 8388608;
  const bool use_pb = ws_size >= (size_t)102236160;

  // scratch overlays in d_out regions written later:
  //  - Xqkb (33.6 MB) at start of P (P written by gemm_sc)
  //  - Xvb (16.8 MB) at start of z; BM bitmask (4.2 MB) right after Xvb
  //    (z region written only by gemm_z, after both are dead)
  unsigned short* Xqkb = (unsigned short*)P;         // [2][8388608] (Xq,Xk)
  unsigned short* Xvb  = (unsigned short*)z;         // [8388608]   (Xv)
  unsigned int*   BM   = (unsigned int*)((unsigned char*)z + 16777216);

  const float inv_scale = 0.21022410381342863f;      // 512^-0.25

  // 1) prep: bf16 conversions + weight transposes + mask bitpack
  prep<<<dim3(8448, 3), 256, 0, stream>>>(
      Xq, Xk, Xv, Xqkb, Xqkb + 8388608, Xvb,
      Wq, Wk, Wv, Wtq, Wtq + 262144, Wtv, mk, BM);

  // 2) Q and K projections in one launch
  proj3<<<dim3(128, 4, 2), 256, 0, stream>>>(
      Xqkb, Wtq, buf1, Wtv, Xvb, buf1, inv_scale, 0);

  // 3) scores: Qs @ Ks^T + bitmask -> P (fp32 logits, masked NEGINF)
  gemm_sc<<<dim3(16, 16, 8), 256, 0, stream>>>(buf1, buf2, P, BM);

  // 4) softmax: P -> attn_p (in place) [+ Pb bf16]
  softmax_rows_f32<<<dim3(16384), 256, 0, stream>>>(P, use_pb ? Pb : nullptr);

  if (use_pb) {
    // 5) Vw^T[b][e][s] into buf1 (Qs dead after scores)
    proj3<<<dim3(32, 16, 1), 256, 0, stream>>>(
        Xqkb, Wtq, buf1, Wtv, Xvb, buf1, inv_scale, 2);
    // 6) z = Pb @ Vwt^T (fp32 out)
    gemm_z<<<dim3(16, 4, 8), 256, 0, stream>>>(Pb, buf1, z);
  } else {
    // fallback: A32 PV (reads fp32 attn_p) + z GEMM
    cvt_t_v<<<dim3(64, 16, 8), 256, 0, stream>>>(Xv, buf1);
    gemm_nt<true, false><<<dim3(16, 4, 8), 256, 0, stream>>>(
        P, buf1, buf2, 2048, 2048, 2048, 512,
        4194304, 1048576, 1048576, 1.0f);
    gemm_nt<false, true><<<dim3(128, 4, 1), 256, 0, stream>>>(
        buf2, Wtv, z, 512, 512, 512, 512, 0, 0, 0, 1.0f);
  }
}

// Round 10
// 541.908 us; speedup vs baseline: 1.0016x; 1.0016x over previous
//
#include <hip/hip_runtime.h>
#include <stdint.h>

typedef __attribute__((ext_vector_type(8))) short short8;
typedef __attribute__((ext_vector_type(4))) float f32x4;
typedef __attribute__((ext_vector_type(4))) int i32x4;
typedef __attribute__((ext_vector_type(8))) unsigned short ushort8v;

#define NEGINF_F (-1000000.0f)
#define MFMA16 __builtin_amdgcn_mfma_f32_16x16x32_bf16

__device__ __forceinline__ unsigned short f2bf(float f) {
  union { float f; uint32_t u; } v; v.f = f;
  uint32_t r = (v.u + 0x7FFFu + ((v.u >> 16) & 1u)) >> 16;
  return (unsigned short)r;
}
__device__ __forceinline__ void gl_lds16(const void* g, void* l) {
  __builtin_amdgcn_global_load_lds(
      (const __attribute__((address_space(1))) void*)g,
      (__attribute__((address_space(3))) void*)l, 16, 0, 0);
}

// ---------------------------------------------------------------------------
// 128x128 GEMM body: C = A @ B^T, bf16 in, mfma 16x16x32 fp32 accum. BK=32,
// 256 thr = 4 waves (2x2), 4x4 frags/wave.
// K-loop: r3/r8-VERIFIED 2-buffer __syncthreads pipeline.
// OUT32: fp32 C via LDS-staged vectorized epilogue.
// MASKED: 1-bit-per-element bitmask (packed in prep) -> NEGINF. Replaces the
// 134 MB int32 mask read (which capped gemm_sc at 3 TB/s, r8 counters) with
// a 4.2 MB L2/L3-resident bit table: one u32 per thread per row-group.
// ---------------------------------------------------------------------------
template<bool OUT32, bool MASKED>
__device__ __forceinline__ void gemm_body(
    const unsigned short* __restrict__ Ap, const unsigned short* __restrict__ Bp,
    void* __restrict__ Cp, const unsigned int* __restrict__ bmp,
    int K, int lda, int ldb, int ldc, int tm, int tn, float scale,
    unsigned short* lds)
{
  const int t = threadIdx.x;
  const int lane = t & 63, wave = t >> 6;
  const int wm = (wave & 1) * 64, wn = (wave >> 1) * 64;
  const int q = lane >> 4, mr = lane & 15;

  f32x4 acc[4][4];
#pragma unroll
  for (int i = 0; i < 4; i++)
#pragma unroll
    for (int j = 0; j < 4; j++) acc[i][j] = (f32x4){0.f, 0.f, 0.f, 0.f};

  const int r0a = t >> 2;                              // staging row
  const int cswz = ((t & 3) ^ ((t >> 2) & 3)) * 8;     // source pre-swizzle
  const int sw8 = (q ^ (mr & 3)) * 8;                  // frag-read swizzle

  auto stage = [&](int bi, int kt) {
    unsigned short* L = lds + bi * 8192;               // A [0,4096) B [4096,8192)
    const int k0 = kt << 5;
    const unsigned short* ga = Ap + (long)(tm + r0a) * lda + k0 + cswz;
    gl_lds16(ga, L + (size_t)t * 8);
    gl_lds16(ga + (long)64 * lda, L + (size_t)(t + 256) * 8);
    unsigned short* Lb = L + 4096;
    const unsigned short* gb = Bp + (long)(tn + r0a) * ldb + k0 + cswz;
    gl_lds16(gb, Lb + (size_t)t * 8);
    gl_lds16(gb + (long)64 * ldb, Lb + (size_t)(t + 256) * 8);
  };

  const int nt = K >> 5;
  stage(0, 0);
  __syncthreads();

  for (int ti = 0; ti < nt; ++ti) {
    if (ti + 1 < nt) stage((ti + 1) & 1, ti + 1);      // prefetch next

    const unsigned short* LA = lds + (ti & 1) * 8192;
    const unsigned short* LB = LA + 4096;
    short8 af[4], bfr[4];
#pragma unroll
    for (int i = 0; i < 4; i++) {
      af[i]  = *(const short8*)&LA[(size_t)(wm + i * 16 + mr) * 32 + sw8];
      bfr[i] = *(const short8*)&LB[(size_t)(wn + i * 16 + mr) * 32 + sw8];
    }
#pragma unroll
    for (int i = 0; i < 4; i++)
#pragma unroll
      for (int j = 0; j < 4; j++)
        acc[i][j] = MFMA16(af[i], bfr[j], acc[i][j], 0, 0, 0);

    if (ti + 1 < nt) __syncthreads();
  }

  // C/D layout (m89-verified): col = lane&15, row = (lane>>4)*4 + reg
  if (OUT32) {
    float* ep = (float*)lds;
    float* co = (float*)Cp;
    const int band = wm >> 2;                 // 0 or 16
    const int tr = t >> 3;                    // 0..31 read row
    const int tcb = (t & 7) * 16;             // read col base (mult of 16)
    const int growb = tm + (tr >> 4) * 64 + (tr & 15);
    const int ldw = ldc >> 5;                 // bitmask words per row
#pragma unroll
    for (int i = 0; i < 4; i++) {
      __syncthreads();
#pragma unroll
      for (int j = 0; j < 4; j++) {
        const int colb = wn + j * 16 + mr;
#pragma unroll
        for (int r = 0; r < 4; r++) {
          const int lr = band + q * 4 + r;
          ep[lr * 128 + ((colb + lr * 4) & 127)] = acc[i][j][r];
        }
      }
      __syncthreads();
      const int gr = growb + i * 16;
      const long rbase = (long)gr * ldc;
      const float* eprow = ep + tr * 128;
      const int rot = tr * 4;
      // one bit-word covers this thread's 16 cols (tn%128==0, tcb%16==0)
      unsigned int mw = 0;
      if (MASKED) mw = bmp[(size_t)gr * ldw + ((tn + tcb) >> 5)];
      const int bb = tcb & 16;                // bit base within the word
#pragma unroll
      for (int k = 0; k < 4; k++) {
        const int lc = tcb + k * 4;
        f32x4 x = *(const f32x4*)&eprow[(lc + rot) & 127];
        x *= scale;
        if (MASKED) {
#pragma unroll
          for (int e = 0; e < 4; e++)
            if (!((mw >> (bb + k * 4 + e)) & 1u)) x[e] = NEGINF_F;
        }
        *(f32x4*)&co[rbase + tn + lc] = x;
      }
    }
  } else {
    unsigned short* co = (unsigned short*)Cp;
#pragma unroll
    for (int i = 0; i < 4; i++)
#pragma unroll
      for (int j = 0; j < 4; j++) {
        const int row0 = tm + wm + i * 16 + q * 4;
        const int col  = tn + wn + j * 16 + mr;
#pragma unroll
        for (int r = 0; r < 4; r++)
          co[(long)(row0 + r) * ldc + col] = f2bf(acc[i][j][r] * scale);
      }
  }
}

// proj3: roles by (blockIdx.z + zoff):
//  z=0/1: Q/K projection  A=Xqkb[z] [16384x512], B=Wt[z], C=QK[z] (bf16, scaled)
//  z=2:   Vw^T per batch  A=Wtv [512x512], B=Xvb_b [2048x512], C=Vwt_b [512x2048]
__global__ __launch_bounds__(256, 4) void proj3(
    const unsigned short* __restrict__ Xqkb, const unsigned short* __restrict__ Wtqk,
    unsigned short* __restrict__ QK,
    const unsigned short* __restrict__ Wtv, const unsigned short* __restrict__ Xvb,
    unsigned short* __restrict__ Vwt, float sc, int zoff)
{
  __shared__ __align__(16) unsigned short lds[16384];
  const int zz = blockIdx.z + zoff;
  if (zz < 2) {
    gemm_body<false, false>(Xqkb + (size_t)zz * 8388608, Wtqk + zz * 262144,
        QK + (size_t)zz * 8388608, nullptr, 512, 512, 512, 512,
        blockIdx.x * 128, blockIdx.y * 128, sc, lds);
  } else {
    const int bb = blockIdx.x >> 2;
    gemm_body<false, false>(Wtv, Xvb + (size_t)bb * 1048576,
        Vwt + (size_t)bb * 1048576, nullptr, 512, 512, 512, 2048,
        (blockIdx.x & 3) * 128, blockIdx.y * 128, 1.0f, lds);
  }
}

// scores: per batch Qs_b @ Ks_b^T, bitmask epilogue -> P fp32
__global__ __launch_bounds__(256, 4) void gemm_sc(
    const unsigned short* __restrict__ Qs, const unsigned short* __restrict__ Ks,
    float* __restrict__ P, const unsigned int* __restrict__ BM)
{
  __shared__ __align__(16) unsigned short lds[16384];
  const int b = blockIdx.z;
  gemm_body<true, true>(Qs + (size_t)b * 1048576, Ks + (size_t)b * 1048576,
      P + (size_t)b * 4194304, BM + (size_t)b * 131072,
      512, 512, 512, 2048, blockIdx.x * 128, blockIdx.y * 128, 1.0f, lds);
}

// z: per batch Pb_b [2048x2048] @ Vwt_b^T [512x2048] -> z fp32 [2048x512]
__global__ __launch_bounds__(256, 4) void gemm_z(
    const unsigned short* __restrict__ Pb, const unsigned short* __restrict__ Vwt,
    float* __restrict__ z)
{
  __shared__ __align__(16) unsigned short lds[16384];
  const int b = blockIdx.z;
  gemm_body<true, false>(Pb + (size_t)b * 4194304, Vwt + (size_t)b * 1048576,
      z + (size_t)b * 1048576, nullptr,
      2048, 2048, 2048, 512, blockIdx.x * 128, blockIdx.y * 128, 1.0f, lds);
}

// ---------------------------------------------------------------------------
// 128x128 gemm_nt (r5-verified): fallback path only (A32 PV + z GEMM).
// ---------------------------------------------------------------------------
template<bool A32, bool OUT32>
__global__ __launch_bounds__(256, A32 ? 2 : 4)
void gemm_nt(const void* __restrict__ Av, const unsigned short* __restrict__ B,
             void* __restrict__ Cv,
             int K, int lda, int ldb, int ldc,
             long sA, long sB, long sC, float scale)
{
  constexpr int ABYTES = A32 ? 128 * 32 * 4 : 128 * 32 * 2;
  constexpr int BBYTES = 128 * 32 * 2;
  constexpr int BUFB = ABYTES + BBYTES;
  __shared__ __align__(16) unsigned char smem[2 * BUFB];

  const int t = threadIdx.x;
  const int b = blockIdx.z;
  const float* Af = (const float*)Av + (long)b * sA;
  const unsigned short* Ah = (const unsigned short*)Av + (long)b * sA;
  const unsigned short* Bp = B + (long)b * sB;
  const int tm = blockIdx.x * 128;
  const int tn = blockIdx.y * 128;

  const int lane = t & 63, wave = t >> 6;
  const int wm = (wave & 1) * 64, wn = (wave >> 1) * 64;
  const int q = lane >> 4, mr = lane & 15;

  f32x4 acc[4][4];
#pragma unroll
  for (int i = 0; i < 4; i++)
#pragma unroll
    for (int j = 0; j < 4; j++) acc[i][j] = (f32x4){0.f, 0.f, 0.f, 0.f};

  const int r0a = t >> 2;
  const int cswz = ((t & 3) ^ ((t >> 2) & 3)) * 8;
  const int sw8 = (q ^ (mr & 3)) * 8;

  auto stage = [&](int buf, int k0) {
    unsigned char* base = smem + buf * BUFB;
    if (A32) {
      float* Asf = (float*)base;
#pragma unroll
      for (int rd = 0; rd < 4; rd++) {
        const int f = rd * 1024 + t * 4;
        const int row = f >> 5, col = f & 31;
        gl_lds16(Af + (long)(tm + row) * lda + k0 + col, Asf + f);
      }
    } else {
      unsigned short* Ash = (unsigned short*)base;
      const unsigned short* ga = Ah + (long)(tm + r0a) * lda + k0 + cswz;
      gl_lds16(ga, &Ash[(size_t)t * 8]);
      gl_lds16(ga + (long)64 * lda, &Ash[(size_t)(t + 256) * 8]);
    }
    unsigned short* Bsb = (unsigned short*)(base + ABYTES);
    const unsigned short* gb = Bp + (long)(tn + r0a) * ldb + k0 + cswz;
    gl_lds16(gb, &Bsb[(size_t)t * 8]);
    gl_lds16(gb + (long)64 * ldb, &Bsb[(size_t)(t + 256) * 8]);
  };

  const int nt = K >> 5;
  stage(0, 0);
  __syncthreads();

  for (int ti = 0; ti < nt; ++ti) {
    if (ti + 1 < nt) stage((ti + 1) & 1, (ti + 1) << 5);

    const unsigned char* base = smem + (ti & 1) * BUFB;
    const unsigned short* Bs = (const unsigned short*)(base + ABYTES);
    short8 af[4], bfr[4];
#pragma unroll
    for (int i = 0; i < 4; i++) {
      if (A32) {
        const float* Asf = (const float*)base;
        const int fb = (wm + i * 16 + mr) * 32 + q * 8;
        const f32x4 x0 = *(const f32x4*)&Asf[fb];
        const f32x4 x1 = *(const f32x4*)&Asf[fb + 4];
        short8 v;
        v[0] = (short)f2bf(x0[0]); v[1] = (short)f2bf(x0[1]);
        v[2] = (short)f2bf(x0[2]); v[3] = (short)f2bf(x0[3]);
        v[4] = (short)f2bf(x1[0]); v[5] = (short)f2bf(x1[1]);
        v[6] = (short)f2bf(x1[2]); v[7] = (short)f2bf(x1[3]);
        af[i] = v;
      } else {
        const unsigned short* Ash = (const unsigned short*)base;
        af[i] = *(const short8*)&Ash[(size_t)(wm + i * 16 + mr) * 32 + sw8];
      }
      bfr[i] = *(const short8*)&Bs[(size_t)(wn + i * 16 + mr) * 32 + sw8];
    }
#pragma unroll
    for (int i = 0; i < 4; i++)
#pragma unroll
      for (int j = 0; j < 4; j++)
        acc[i][j] = MFMA16(af[i], bfr[j], acc[i][j], 0, 0, 0);

    if (ti + 1 < nt) __syncthreads();
  }

  if (OUT32) {
    float* ep = (float*)smem;
    float* co = (float*)Cv + (long)b * sC;
    const int band = wm >> 2;
    const int tr = t >> 3;
    const int tcb = (t & 7) * 16;
    const int growb = tm + (tr >> 4) * 64 + (tr & 15);
#pragma unroll
    for (int i = 0; i < 4; i++) {
      __syncthreads();
#pragma unroll
      for (int j = 0; j < 4; j++) {
        const int colb = wn + j * 16 + mr;
#pragma unroll
        for (int r = 0; r < 4; r++) {
          const int lr = band + q * 4 + r;
          ep[lr * 128 + ((colb + lr * 4) & 127)] = acc[i][j][r];
        }
      }
      __syncthreads();
      const int gr = growb + i * 16;
      const long rbase = (long)gr * ldc;
      const float* eprow = ep + tr * 128;
      const int rot = tr * 4;
#pragma unroll
      for (int k = 0; k < 4; k++) {
        const int lc = tcb + k * 4;
        f32x4 x = *(const f32x4*)&eprow[(lc + rot) & 127];
        x *= scale;
        *(f32x4*)&co[rbase + tn + lc] = x;
      }
    }
  } else {
#pragma unroll
    for (int i = 0; i < 4; i++) {
#pragma unroll
      for (int j = 0; j < 4; j++) {
        const int row0 = tm + wm + i * 16 + q * 4;
        const int col  = tn + wn + j * 16 + mr;
        const f32x4 v = acc[i][j];
#pragma unroll
        for (int r = 0; r < 4; r++) {
          float x = v[r] * scale;
          ((unsigned short*)Cv + (long)b * sC)[(long)(row0 + r) * ldc + col] = f2bf(x);
        }
      }
    }
  }
}

// one block per row of 2048 fp32 logits (mask pre-applied as NEGINF upstream):
// max -> sumexp -> normalize in place; optional bf16 copy to Pb.
__global__ __launch_bounds__(256) void softmax_rows_f32(
    float* __restrict__ P, unsigned short* __restrict__ Pb)
{
  const size_t row = blockIdx.x;
  float* p = P + row * 2048;
  const int t = threadIdx.x, lane = t & 63, wv = t >> 6;
  f32x4 a = *(const f32x4*)(p + t * 8);
  f32x4 c = *(const f32x4*)(p + t * 8 + 4);
  float x[8] = {a[0], a[1], a[2], a[3], c[0], c[1], c[2], c[3]};
  float mx = x[0];
#pragma unroll
  for (int j = 1; j < 8; j++) mx = fmaxf(mx, x[j]);
#pragma unroll
  for (int o = 32; o > 0; o >>= 1) mx = fmaxf(mx, __shfl_xor(mx, o));
  __shared__ float rm[4], rs[4];
  if (lane == 0) rm[wv] = mx;
  __syncthreads();
  mx = fmaxf(fmaxf(rm[0], rm[1]), fmaxf(rm[2], rm[3]));
  float e[8], s = 0.f;
#pragma unroll
  for (int j = 0; j < 8; j++) { e[j] = __expf(x[j] - mx); s += e[j]; }
#pragma unroll
  for (int o = 32; o > 0; o >>= 1) s += __shfl_xor(s, o);
  if (lane == 0) rs[wv] = s;
  __syncthreads();
  s = rs[0] + rs[1] + rs[2] + rs[3];
  // fully-masked row: mx stays NEGINF -> reference (softmax * mask) = 0
  const float linv = (mx < -1.0e5f) ? 0.f : 1.f / s;
  f32x4 o0 = {e[0] * linv, e[1] * linv, e[2] * linv, e[3] * linv};
  f32x4 o1 = {e[4] * linv, e[5] * linv, e[6] * linv, e[7] * linv};
  *(f32x4*)(p + t * 8) = o0;
  *(f32x4*)(p + t * 8 + 4) = o1;
  if (Pb) {
    ushort8v ob;
    ob[0] = f2bf(o0[0]); ob[1] = f2bf(o0[1]); ob[2] = f2bf(o0[2]); ob[3] = f2bf(o0[3]);
    ob[4] = f2bf(o1[0]); ob[5] = f2bf(o1[1]); ob[6] = f2bf(o1[2]); ob[7] = f2bf(o1[3]);
    *(ushort8v*)(Pb + row * 2048 + t * 8) = ob;
  }
}

// per-batch transpose+convert (fallback path only)
__global__ __launch_bounds__(256) void cvt_t_v(
    const float* __restrict__ src, unsigned short* __restrict__ dst)
{
  const int b = blockIdx.z;
  __shared__ float tile[32][33];
  const int s0 = blockIdx.x * 32, i0 = blockIdx.y * 32;
  const int tx = threadIdx.x & 31, ty = threadIdx.x >> 5;
#pragma unroll
  for (int r = 0; r < 4; r++) {
    const int srow = ty + r * 8;
    tile[srow][tx] = src[((size_t)b * 2048 + s0 + srow) * 512 + i0 + tx];
  }
  __syncthreads();
#pragma unroll
  for (int r = 0; r < 4; r++) {
    const int irow = ty + r * 8;
    dst[((size_t)b * 512 + i0 + irow) * 2048 + s0 + tx] = f2bf(tile[tx][irow]);
  }
}

// prep: fused cvt3 (x<4096) + transpose_w (4096<=x<4352) + mask bitpack
// (y==0, 4352<=x<8448). Bitpack is LDS-coalesced: 256 thr x 8 rounds of
// contiguous i32x4 loads (1 KB/wave-instr) -> predicate bytes in LDS ->
// each thread packs bytes [t*32, t*32+32) into one u32. (r9's per-thread
// direct packing read at 128B lane stride and sank prep to 1.78 TB/s.)
__global__ __launch_bounds__(256) void prep(
    const float* __restrict__ Xq, const float* __restrict__ Xk,
    const float* __restrict__ Xv,
    unsigned short* __restrict__ dq, unsigned short* __restrict__ dk,
    unsigned short* __restrict__ dv,
    const float* __restrict__ W0, const float* __restrict__ W1,
    const float* __restrict__ W2,
    unsigned short* __restrict__ T0, unsigned short* __restrict__ T1,
    unsigned short* __restrict__ T2,
    const int* __restrict__ mk, unsigned int* __restrict__ BM)
{
  const int y = blockIdx.y;
  if (blockIdx.x < 4096) {
    const float* s = y == 0 ? Xq : (y == 1 ? Xk : Xv);
    unsigned short* d = y == 0 ? dq : (y == 1 ? dk : dv);
    const size_t i = ((size_t)blockIdx.x * 256 + threadIdx.x) * 8;
    const float4 a = *(const float4*)(s + i);
    const float4 b = *(const float4*)(s + i + 4);
    ushort8v o;
    o[0] = f2bf(a.x); o[1] = f2bf(a.y); o[2] = f2bf(a.z); o[3] = f2bf(a.w);
    o[4] = f2bf(b.x); o[5] = f2bf(b.y); o[6] = f2bf(b.z); o[7] = f2bf(b.w);
    *(ushort8v*)(d + i) = o;
  } else if (blockIdx.x < 4352) {
    const float* W = y == 0 ? W0 : (y == 1 ? W1 : W2);
    unsigned short* T = y == 0 ? T0 : (y == 1 ? T1 : T2);
    __shared__ float tile[32][33];
    const int id = blockIdx.x - 4096;            // 0..255 -> 16x16 tiles
    const int bx = (id & 15) * 32, by = (id >> 4) * 32;
    const int tx = threadIdx.x & 31, ty = threadIdx.x >> 5;
#pragma unroll
    for (int i = 0; i < 4; i++) {
      const int r = ty + i * 8;
      tile[r][tx] = W[(size_t)(by + r) * 512 + bx + tx];
    }
    __syncthreads();
#pragma unroll
    for (int i = 0; i < 4; i++) {
      const int r = ty + i * 8;
      T[(size_t)(bx + r) * 512 + by + tx] = f2bf(tile[tx][r]);
    }
  } else if (y == 0) {
    // coalesced bitpack: block covers 8192 ints (32 KB of mask)
    __shared__ unsigned char pred[8192];
    const size_t base = (size_t)(blockIdx.x - 4352) * 8192;
    const int* mp = mk + base;
    const int t = threadIdx.x;
#pragma unroll
    for (int r = 0; r < 8; r++) {
      const int idx = r * 1024 + t * 4;          // contiguous across lanes
      const i32x4 v = *(const i32x4*)(mp + idx);
      const unsigned int pb = (v[0] != 0 ? 1u : 0u)
                            | (v[1] != 0 ? 0x100u : 0u)
                            | (v[2] != 0 ? 0x10000u : 0u)
                            | (v[3] != 0 ? 0x1000000u : 0u);
      *(unsigned int*)&pred[idx] = pb;
    }
    __syncthreads();
    unsigned int bits = 0;
    const int wb = t * 32;
#pragma unroll
    for (int k = 0; k < 8; k++) {
      const unsigned int pw = *(const unsigned int*)&pred[wb + k * 4];
      bits |= (pw & 1u) << (k * 4)
           |  ((pw >> 8) & 1u) << (k * 4 + 1)
           |  ((pw >> 16) & 1u) << (k * 4 + 2)
           |  ((pw >> 24) & 1u) << (k * 4 + 3);
    }
    BM[base / 32 + t] = bits;
  }
}

extern "C" void kernel_launch(void* const* d_in, const int* in_sizes, int n_in,
                              void* d_out, int out_size, void* d_ws, size_t ws_size,
                              hipStream_t stream) {
  const float* Xq = (const float*)d_in[0];
  const float* Xk = (const float*)d_in[1];
  const float* Xv = (const float*)d_in[2];
  const int*   mk = (const int*)d_in[3];
  const float* Wq = (const float*)d_in[4];
  const float* Wk = (const float*)d_in[5];
  const float* Wv = (const float*)d_in[6];

  float* z = (float*)d_out;                          // [8,2048,512] fp32
  float* P = z + (size_t)8 * 2048 * 512;             // [8,2048,2048] fp32

  // ws layout (bf16 shorts): Wtq|Wtk|Wtv (3x262144), buf1 (8388608),
  // buf2 (8388608), Pb (33554432) -> 102236160 bytes total.
  unsigned short* w    = (unsigned short*)d_ws;
  unsigned short* Wtq  = w;
  unsigned short* Wtv  = w + 524288;
  unsigned short* buf1 = w + 786432;                 // Qs; later Vwt
  unsigned short* buf2 = buf1 + 8388608;             // Ks
  unsigned short* Pb   = buf2 + 8388608;
  const bool use_pb = ws_size >= (size_t)102236160;

  // scratch overlays in d_out regions written later:
  //  - Xqkb (33.6 MB) at start of P (P written by gemm_sc)
  //  - Xvb (16.8 MB) at start of z; BM bitmask (4.2 MB) right after Xvb
  //    (z region written only by gemm_z, after both are dead)
  unsigned short* Xqkb = (unsigned short*)P;         // [2][8388608] (Xq,Xk)
  unsigned short* Xvb  = (unsigned short*)z;         // [8388608]   (Xv)
  unsigned int*   BM   = (unsigned int*)((unsigned char*)z + 16777216);

  const float inv_scale = 0.21022410381342863f;      // 512^-0.25

  // 1) prep: bf16 conversions + weight transposes + mask bitpack
  prep<<<dim3(8448, 3), 256, 0, stream>>>(
      Xq, Xk, Xv, Xqkb, Xqkb + 8388608, Xvb,
      Wq, Wk, Wv, Wtq, Wtq + 262144, Wtv, mk, BM);

  // 2) Q and K projections in one launch
  proj3<<<dim3(128, 4, 2), 256, 0, stream>>>(
      Xqkb, Wtq, buf1, Wtv, Xvb, buf1, inv_scale, 0);

  // 3) scores: Qs @ Ks^T + bitmask -> P (fp32 logits, masked NEGINF)
  gemm_sc<<<dim3(16, 16, 8), 256, 0, stream>>>(buf1, buf2, P, BM);

  // 4) softmax: P -> attn_p (in place) [+ Pb bf16]
  softmax_rows_f32<<<dim3(16384), 256, 0, stream>>>(P, use_pb ? Pb : nullptr);

  if (use_pb) {
    // 5) Vw^T[b][e][s] into buf1 (Qs dead after scores)
    proj3<<<dim3(32, 16, 1), 256, 0, stream>>>(
        Xqkb, Wtq, buf1, Wtv, Xvb, buf1, inv_scale, 2);
    // 6) z = Pb @ Vwt^T (fp32 out)
    gemm_z<<<dim3(16, 4, 8), 256, 0, stream>>>(Pb, buf1, z);
  } else {
    // fallback: A32 PV (reads fp32 attn_p) + z GEMM
    cvt_t_v<<<dim3(64, 16, 8), 256, 0, stream>>>(Xv, buf1);
    gemm_nt<true, false><<<dim3(16, 4, 8), 256, 0, stream>>>(
        P, buf1, buf2, 2048, 2048, 2048, 512,
        4194304, 1048576, 1048576, 1.0f);
    gemm_nt<false, true><<<dim3(128, 4, 1), 256, 0, stream>>>(
        buf2, Wtv, z, 512, 512, 512, 512, 0, 0, 0, 1.0f);
  }
}